// Round 18
// baseline (1100.307 us; speedup 1.0000x reference)
//
#include <hip/hip_runtime.h>
#include <hip/hip_bf16.h>

using bf16 = __hip_bfloat16;
typedef __attribute__((ext_vector_type(8))) short short8;
typedef __attribute__((ext_vector_type(4))) float f32x4;
typedef __attribute__((ext_vector_type(4))) unsigned int u32x4;

static __device__ __forceinline__ float b2f(unsigned short s) {
    unsigned u = ((unsigned)s) << 16;
    return __builtin_bit_cast(float, u);
}
static __device__ __forceinline__ short f2b(float f) {
    __hip_bfloat16 h = __float2bfloat16(f);
    return __builtin_bit_cast(short, h);
}
static __device__ __forceinline__ void load_lds16(const void* g, void* l) {
    __builtin_amdgcn_global_load_lds(
        (const __attribute__((address_space(1))) void*)g,
        (__attribute__((address_space(3))) void*)l, 16, 0, 0);
}

// ---------------- f32 -> bf16 conversion (8 elems/thread) ----------------
__global__ void f32_to_bf16_vec(const float* __restrict__ in, bf16* __restrict__ out, int n8) {
    int i = blockIdx.x * blockDim.x + threadIdx.x;
    if (i >= n8) return;
    const f32x4* p = (const f32x4*)(in + (size_t)i * 8);
    f32x4 a = p[0], b = p[1];
    short8 o;
    o[0] = f2b(a[0]); o[1] = f2b(a[1]); o[2] = f2b(a[2]); o[3] = f2b(a[3]);
    o[4] = f2b(b[0]); o[5] = f2b(b[1]); o[6] = f2b(b[2]); o[7] = f2b(b[3]);
    *(short8*)(out + (size_t)i * 8) = o;
}

// ---------------- fused GEMM + bias + relu + LayerNorm (Nout = 512) ----------------
template<int K, bool CONV>
__global__ __launch_bounds__(512, 2) void gemm_ln_fused(
    const void* __restrict__ Xv, const bf16* __restrict__ W,
    const float* __restrict__ bias, const float* __restrict__ g,
    const float* __restrict__ be, bf16* __restrict__ Y)
{
    __shared__ char As[8192];     // 128 rows x 64B (swizzled)
    __shared__ char Bs[32768];    // 512 rows x 64B (swizzled)
    __shared__ float lnS[128][4];
    __shared__ float lnQ[128][4];

    const int tid = threadIdx.x;
    const int wv = tid >> 6, lane = tid & 63;
    const int wr = wv >> 2, wc = wv & 3;
    const long Mbase = (long)blockIdx.x * 128;
    const int lc = lane & 15, kgq = lane >> 4;

    f32x4 acc[4][8];
#pragma unroll
    for (int mt = 0; mt < 4; ++mt)
#pragma unroll
        for (int nt = 0; nt < 8; ++nt) acc[mt][nt] = (f32x4){0.f, 0.f, 0.f, 0.f};

    const int rowA_ = tid >> 2, granA_ = tid & 3;

    for (int kb = 0; kb < K / 32; ++kb) {
        __syncthreads();
        {   // stage A: 128 x 64B
            const int sb = (granA_ * 16) ^ (((rowA_ >> 1) & 3) << 4);
            if (CONV) {
                const float* Xf = (const float*)Xv;
                const float* src = Xf + (Mbase + rowA_) * K + kb * 32 + sb / 2;
                f32x4 a0 = *(const f32x4*)src;
                f32x4 a1 = *(const f32x4*)(src + 4);
                short8 o;
                o[0] = f2b(a0[0]); o[1] = f2b(a0[1]); o[2] = f2b(a0[2]); o[3] = f2b(a0[3]);
                o[4] = f2b(a1[0]); o[5] = f2b(a1[1]); o[6] = f2b(a1[2]); o[7] = f2b(a1[3]);
                *(short8*)(As + rowA_ * 64 + granA_ * 16) = o;
            } else {
                const bf16* X = (const bf16*)Xv;
                load_lds16((const char*)X + ((Mbase + rowA_) * K + kb * 32) * 2 + sb,
                           As + tid * 16);
            }
        }
#pragma unroll
        for (int j = 0; j < 4; ++j) {   // stage B: 512 x 64B
            const int idx = j * 512 + tid;
            const int row = idx >> 2, gran = idx & 3;
            const int sb = (gran * 16) ^ (((row >> 1) & 3) << 4);
            load_lds16((const char*)W + ((long)row * K + kb * 32) * 2 + sb,
                       Bs + idx * 16);
        }
        __syncthreads();

        short8 a[4], b[8];
#pragma unroll
        for (int mt = 0; mt < 4; ++mt) {
            const int ar = wr * 64 + mt * 16 + lc;
            a[mt] = *(const short8*)(As + ar * 64 + ((kgq * 16) ^ (((ar >> 1) & 3) << 4)));
        }
#pragma unroll
        for (int nt = 0; nt < 8; ++nt) {
            const int br = wc * 128 + nt * 16 + lc;
            b[nt] = *(const short8*)(Bs + br * 64 + ((kgq * 16) ^ (((br >> 1) & 3) << 4)));
        }
#pragma unroll
        for (int mt = 0; mt < 4; ++mt)
#pragma unroll
            for (int nt = 0; nt < 8; ++nt)
                acc[mt][nt] = __builtin_amdgcn_mfma_f32_16x16x32_bf16(a[mt], b[nt], acc[mt][nt], 0, 0, 0);
    }

    float bcol[8];
#pragma unroll
    for (int nt = 0; nt < 8; ++nt) bcol[nt] = bias[wc * 128 + nt * 16 + lc];

    float sp[4][4], qp[4][4];
#pragma unroll
    for (int mt = 0; mt < 4; ++mt)
#pragma unroll
        for (int r = 0; r < 4; ++r) { sp[mt][r] = 0.f; qp[mt][r] = 0.f; }
#pragma unroll
    for (int mt = 0; mt < 4; ++mt)
#pragma unroll
        for (int nt = 0; nt < 8; ++nt)
#pragma unroll
            for (int r = 0; r < 4; ++r) {
                float v = fmaxf(acc[mt][nt][r] + bcol[nt], 0.f);
                acc[mt][nt][r] = v;
                sp[mt][r] += v; qp[mt][r] += v * v;
            }
#pragma unroll
    for (int m = 1; m < 16; m <<= 1)
#pragma unroll
        for (int mt = 0; mt < 4; ++mt)
#pragma unroll
            for (int r = 0; r < 4; ++r) {
                sp[mt][r] += __shfl_xor(sp[mt][r], m);
                qp[mt][r] += __shfl_xor(qp[mt][r], m);
            }
    if (lc == 0) {
#pragma unroll
        for (int mt = 0; mt < 4; ++mt)
#pragma unroll
            for (int r = 0; r < 4; ++r) {
                const int grow = wr * 64 + mt * 16 + kgq * 4 + r;
                lnS[grow][wc] = sp[mt][r];
                lnQ[grow][wc] = qp[mt][r];
            }
    }
    __syncthreads();

    float gcol[8], becol[8];
#pragma unroll
    for (int nt = 0; nt < 8; ++nt) {
        const int col = wc * 128 + nt * 16 + lc;
        gcol[nt] = g[col]; becol[nt] = be[col];
    }
#pragma unroll
    for (int mt = 0; mt < 4; ++mt)
#pragma unroll
        for (int r = 0; r < 4; ++r) {
            const int grow = wr * 64 + mt * 16 + kgq * 4 + r;
            f32x4 vs = *(const f32x4*)&lnS[grow][0];
            f32x4 vq = *(const f32x4*)&lnQ[grow][0];
            const float s = vs[0] + vs[1] + vs[2] + vs[3];
            const float q = vq[0] + vq[1] + vq[2] + vq[3];
            const float mu   = s * (1.f / 512.f);
            const float var  = q * (1.f / 512.f) - mu * mu;
            const float rstd = rsqrtf(var + 1e-5f);
            bf16* yrow = Y + (Mbase + grow) * 512;
#pragma unroll
            for (int nt = 0; nt < 8; ++nt) {
                const int col = wc * 128 + nt * 16 + lc;
                yrow[col] = __float2bfloat16((acc[mt][nt][r] - mu) * rstd * gcol[nt] + becol[nt]);
            }
        }
}

// ---------------- GEMM: C = X @ W^T + bias (M from blockIdx.y, N from blockIdx.x) ----
template<int K, bool RELU>
__global__ __launch_bounds__(256) void gemm_xwt(
    const bf16* __restrict__ X, const bf16* __restrict__ W,
    const float* __restrict__ bias, bf16* __restrict__ C, int Nout)
{
    __shared__ char As[8192];
    __shared__ char Bs[8192];
    const int tid  = threadIdx.x;
    const int wave = tid >> 6, lane = tid & 63;
    const int wr = wave >> 1, wc = wave & 1;
    const long Mbase = (long)blockIdx.y * 128;
    const int  Nbase = blockIdx.x * 128;
    const int lc = lane & 15, kgq = lane >> 4;

    f32x4 acc[4][4];
#pragma unroll
    for (int i = 0; i < 4; ++i)
#pragma unroll
        for (int j = 0; j < 4; ++j) acc[i][j] = (f32x4){0.f, 0.f, 0.f, 0.f};

    const int row0_ = tid >> 2, gran_ = tid & 3;

    for (int kb = 0; kb < K / 32; ++kb) {
        __syncthreads();
#pragma unroll
        for (int q = 0; q < 2; ++q) {
            const int idx = q * 256 + tid;
            const int row = q * 64 + row0_;
            const int sb = (gran_ * 16) ^ (((row >> 1) & 3) << 4);
            load_lds16((const char*)X + ((Mbase + row) * K + kb * 32) * 2 + sb,
                       As + idx * 16);
            load_lds16((const char*)W + ((long)(Nbase + row) * K + kb * 32) * 2 + sb,
                       Bs + idx * 16);
        }
        __syncthreads();

        short8 a[4], b[4];
#pragma unroll
        for (int mt = 0; mt < 4; ++mt) {
            const int ar = wr * 64 + mt * 16 + lc;
            a[mt] = *(const short8*)(As + ar * 64 + ((kgq * 16) ^ (((ar >> 1) & 3) << 4)));
        }
#pragma unroll
        for (int nt = 0; nt < 4; ++nt) {
            const int br = wc * 64 + nt * 16 + lc;
            b[nt] = *(const short8*)(Bs + br * 64 + ((kgq * 16) ^ (((br >> 1) & 3) << 4)));
        }
#pragma unroll
        for (int mt = 0; mt < 4; ++mt)
#pragma unroll
            for (int nt = 0; nt < 4; ++nt)
                acc[mt][nt] = __builtin_amdgcn_mfma_f32_16x16x32_bf16(a[mt], b[nt], acc[mt][nt], 0, 0, 0);
    }

#pragma unroll
    for (int mt = 0; mt < 4; ++mt) {
        int row0 = wr * 64 + mt * 16 + (lane >> 4) * 4;
#pragma unroll
        for (int nt = 0; nt < 4; ++nt) {
            int col = Nbase + wc * 64 + nt * 16 + (lane & 15);
            float bv = bias[col];
#pragma unroll
            for (int r = 0; r < 4; ++r) {
                float v = acc[mt][nt][r] + bv;
                if (RELU) v = fmaxf(v, 0.f);
                C[(Mbase + row0 + r) * (long)Nout + col] = __float2bfloat16(v);
            }
        }
    }
}

// ---------------- GRU scan v17: fused LN with sums computed in-register ----------------
// vs v16 (R17): LN row sums are computed from the staging REGISTERS (hv[]) with a
// 64-lane shuffle reduce during phase [3] -- no LDS re-read (R17's 8-way-conflict
// phase [6] removed), no extra barrier (lnSs covered by the existing syncthreads).
// All correctness logic identical to the R17-passing kernel: unmasked h exchange,
// bitwise A-frag masking, lagged out(t-1), epilogue round 129.
__global__ __launch_bounds__(256, 1) void gru_scan17(
    const bf16* __restrict__ gi, const float* __restrict__ on_reset,
    const float* __restrict__ hx, const bf16* __restrict__ Whh,
    const float* __restrict__ bhh, const float* __restrict__ gr,
    const float* __restrict__ br,
    bf16* __restrict__ hA, bf16* __restrict__ hB,
    float* __restrict__ out, float* __restrict__ hT,
    unsigned* __restrict__ bar)
{
    __shared__ bf16 Wl[96 * 512];   // 98304 B, XOR-swizzled storage
    __shared__ bf16 hS[32 * 512];   // 32768 B, XOR-swizzled storage, UNMASKED h
    __shared__ float mrow[32];      // m_t for the group's 32 rows
    __shared__ float lnSs[32];      // full-row sum of staged h
    __shared__ float lnQq[32];      // full-row sum of staged h^2

    const int tid = threadIdx.x;
    const int bid = blockIdx.x;
    const int xcd = bid & 7, sub = bid >> 3;
    const int g   = xcd * 2 + (sub & 1);          // batch-chunk 0..15
    const int cc  = sub >> 1;                     // col-chunk 0..15
    const int n0 = g * 32, c0 = cc * 32;
    unsigned* gflags = bar + g * 512;             // 16 flags x 128B stride
    unsigned* myflag = gflags + cc * 32;

    const int w = tid >> 6, lane = tid & 63;
    const int lc = lane & 15, kg = lane >> 4;
    const int rt = w >> 1, hh = w & 1;
    const int cg = c0 + hh * 16 + lc;

    char* Wlb = (char*)Wl;
    char* hSb = (char*)hS;

    // ---- Wl: DMA the 96-row Whh slice once ----
    {
        const char* Wb = (const char*)Whh;
#pragma unroll
        for (int i2 = 0; i2 < 24; ++i2) {
            const int i = i2 * 256 + tid;
            const int row = i >> 6, l16 = i & 63;
            const int gRow = (row >> 5) * 512 + c0 + (row & 31);
            load_lds16(Wb + (size_t)gRow * 1024 + ((l16 * 16) ^ ((row & 7) << 4)),
                       Wlb + i * 16);
        }
    }

    const float bhr = bhh[cg], bhz = bhh[512 + cg], bhn = bhh[1024 + cg];
    const float grg = gr[cg], brb = br[cg];

    // ---- h0 init: UNMASKED bf16(hx) to hA ----
    float hreg[4];
#pragma unroll
    for (int r = 0; r < 4; ++r) {
        const int row = rt * 16 + kg * 4 + r;
        float v = hx[(size_t)(n0 + row) * 512 + cg];
        hreg[r] = v;
        hA[(size_t)(n0 + row) * 512 + cg] = __float2bfloat16(v);
    }
    __syncthreads();
    asm volatile("s_waitcnt vmcnt(0)" ::: "memory");
    if (tid == 0)
        __hip_atomic_store(myflag, 1u, __ATOMIC_RELEASE, __HIP_MEMORY_SCOPE_AGENT);

#pragma unroll 1
    for (int t = 0; t < 128; ++t) {
        const bf16* hcur = (t & 1) ? hB : hA;
        bf16*       hnxt = (t & 1) ? hA : hB;

        // [1] gi + masks issued early (overlap the poll); mrow for all 32 rows
        float irv[4], izv[4], inv_[4], mcur[4];
#pragma unroll
        for (int r = 0; r < 4; ++r) {
            const int row = rt * 16 + kg * 4 + r;
            const unsigned short* gp =
                (const unsigned short*)gi + ((size_t)t * 512 + n0 + row) * 1536;
            irv[r]  = b2f(__builtin_nontemporal_load(gp + cg));
            izv[r]  = b2f(__builtin_nontemporal_load(gp + 512 + cg));
            inv_[r] = b2f(__builtin_nontemporal_load(gp + 1024 + cg));
            mcur[r] = on_reset[(size_t)t * 512 + n0 + row];
        }
        if (tid < 32) mrow[tid] = on_reset[(size_t)t * 512 + n0 + tid];

        // [2] distributed-flag barrier: sc0/sc1 read-through poll
        if (w == 0) {
            const unsigned tgt = (unsigned)(t + 1);
            const unsigned* fp = gflags + (lane & 15) * 32;
            for (;;) {
                unsigned v = tgt;
                if (lane < 16) {
                    asm volatile("global_load_dword %0, %1, off sc0 sc1\n\t"
                                 "s_waitcnt vmcnt(0)"
                                 : "=v"(v) : "v"(fp) : "memory");
                }
                if (__all(v >= tgt)) break;
                __builtin_amdgcn_s_sleep(2);
            }
        }
        __syncthreads();   // h published by all 16 blocks; mrow visible

        // [3] stage h (UNMASKED) + in-register LN row sums
        {
            const char* hbp = (const char*)hcur + (size_t)n0 * 1024;
            u32x4 hv[8];
#pragma unroll
            for (int j = 0; j < 8; ++j) {
                const int i = j * 256 + tid;
                const int row = i >> 6, l16 = i & 63;
                const char* src = hbp + row * 1024 + l16 * 16;
                asm volatile("global_load_dwordx4 %0, %1, off sc0 sc1"
                             : "=v"(hv[j]) : "v"(src));
            }
            asm volatile("s_waitcnt vmcnt(0)" ::: "memory");
            __builtin_amdgcn_sched_barrier(0);
#pragma unroll
            for (int j = 0; j < 8; ++j) {
                const int i = j * 256 + tid;
                const int row = i >> 6, l16 = i & 63;
                *(u32x4*)(hSb + row * 1024 + ((l16 * 16) ^ ((row & 7) << 4))) = hv[j];
            }
            // in-register row sums: wave w, iter j holds row j*4+w across 64 lanes
#pragma unroll
            for (int j = 0; j < 8; ++j) {
                float s = 0.f, q = 0.f;
#pragma unroll
                for (int d = 0; d < 4; ++d) {
                    const float f0 = b2f((unsigned short)(hv[j][d] & 0xffff));
                    const float f1 = b2f((unsigned short)(hv[j][d] >> 16));
                    s += f0 + f1; q += f0 * f0 + f1 * f1;
                }
#pragma unroll
                for (int m = 1; m < 64; m <<= 1) {
                    s += __shfl_xor(s, m);
                    q += __shfl_xor(q, m);
                }
                if (lane == 0) { lnSs[j * 4 + w] = s; lnQq[j * 4 + w] = q; }
            }
        }
        __syncthreads();   // hS + lnSs/lnQq ready

        // [7] out(t-1): staged h == h_{t-1}; hreg still holds h_{t-1}
        if (t > 0) {
#pragma unroll
            for (int r = 0; r < 4; ++r) {
                const int row = rt * 16 + kg * 4 + r;
                const float mu   = lnSs[row] * (1.f / 512.f);
                const float var  = lnQq[row] * (1.f / 512.f) - mu * mu;
                const float rstd = rsqrtf(var + 1e-5f);
                const float o = (hreg[r] - mu) * rstd * grg + brb;
                __builtin_nontemporal_store(
                    o, out + ((size_t)(t - 1) * 512 + n0 + row) * 512 + cg);
            }
        }

        // [4] A-frags from hS, masked by m_t (bitwise AND; m is exactly 0 or 1)
        short8 aF[16];
        const int arow = rt * 16 + lc;
        const int asw = (arow & 7) << 4;
        const unsigned mb = (mrow[arow] == 0.f) ? 0u : 0xffffffffu;
#pragma unroll
        for (int kc = 0; kc < 16; ++kc) {
            u32x4 av = *(const u32x4*)(hSb + arow * 1024 + ((kc * 64 + kg * 16) ^ asw));
            av[0] &= mb; av[1] &= mb; av[2] &= mb; av[3] &= mb;
            aF[kc] = __builtin_bit_cast(short8, av);
        }

        // [5] MFMA: 3 gates x 16 k-slices
        f32x4 acc[3];
#pragma unroll
        for (int gt = 0; gt < 3; ++gt) acc[gt] = (f32x4){0.f, 0.f, 0.f, 0.f};
#pragma unroll
        for (int gt = 0; gt < 3; ++gt) {
            const int wrow = gt * 32 + hh * 16 + lc;
            const int wsw = (wrow & 7) << 4;
#pragma unroll
            for (int kc = 0; kc < 16; ++kc) {
                short8 bq = *(const short8*)(Wlb + wrow * 1024 + ((kc * 64 + kg * 16) ^ wsw));
                acc[gt] = __builtin_amdgcn_mfma_f32_16x16x32_bf16(aF[kc], bq, acc[gt], 0, 0, 0);
            }
        }

        // [8] gates + h update + UNMASKED h store (write-through exchange)
#pragma unroll
        for (int r = 0; r < 4; ++r) {
            const int row = rt * 16 + kg * 4 + r;
            const float hr = acc[0][r] + bhr;
            const float hz = acc[1][r] + bhz;
            const float hn = acc[2][r] + bhn;
            const float rg = 1.f / (1.f + __expf(-(irv[r] + hr)));
            const float zg = 1.f / (1.f + __expf(-(izv[r] + hz)));
            const float e2 = __expf(2.f * (inv_[r] + rg * hn));
            const float ng = 1.f - 2.f / (e2 + 1.f);   // tanh
            const float hv = (1.f - zg) * ng + zg * (hreg[r] * mcur[r]);
            hreg[r] = hv;
            const unsigned short hb16 = (unsigned short)f2b(hv);
            const unsigned partner = (unsigned)(unsigned short)__shfl_xor((int)hb16, 1);
            if ((lc & 1) == 0) {
                const unsigned pk = (unsigned)hb16 | (partner << 16);
                unsigned* dst = (unsigned*)&hnxt[(size_t)(n0 + row) * 512 + cg];
                asm volatile("global_store_dword %0, %1, off sc0 sc1"
                             :: "v"(dst), "v"(pk) : "memory");
            }
        }

        __syncthreads();   // drains vmcnt: all waves' sc1 stores at coherence point
        if (tid == 0) {
            unsigned fv = (unsigned)(t + 2);
            asm volatile("global_store_dword %0, %1, off sc0 sc1"
                         :: "v"(myflag), "v"(fv) : "memory");
        }
    }

    // ---- epilogue: wait round 129, read h_127, in-register LN, out(127) + hT ----
    if (w == 0) {
        const unsigned tgt = 129u;
        const unsigned* fp = gflags + (lane & 15) * 32;
        for (;;) {
            unsigned v = tgt;
            if (lane < 16) {
                asm volatile("global_load_dword %0, %1, off sc0 sc1\n\t"
                             "s_waitcnt vmcnt(0)"
                             : "=v"(v) : "v"(fp) : "memory");
            }
            if (__all(v >= tgt)) break;
            __builtin_amdgcn_s_sleep(2);
        }
    }
    __syncthreads();
    {
        const bf16* hcur = hA;   // t=128: (128&1)==0 -> hA (written at t=127)
        const char* hbp = (const char*)hcur + (size_t)n0 * 1024;
        u32x4 hv[8];
#pragma unroll
        for (int j = 0; j < 8; ++j) {
            const int i = j * 256 + tid;
            const int row = i >> 6, l16 = i & 63;
            const char* src = hbp + row * 1024 + l16 * 16;
            asm volatile("global_load_dwordx4 %0, %1, off sc0 sc1"
                         : "=v"(hv[j]) : "v"(src));
        }
        asm volatile("s_waitcnt vmcnt(0)" ::: "memory");
        __builtin_amdgcn_sched_barrier(0);
#pragma unroll
        for (int j = 0; j < 8; ++j) {
            float s = 0.f, q = 0.f;
#pragma unroll
            for (int d = 0; d < 4; ++d) {
                const float f0 = b2f((unsigned short)(hv[j][d] & 0xffff));
                const float f1 = b2f((unsigned short)(hv[j][d] >> 16));
                s += f0 + f1; q += f0 * f0 + f1 * f1;
            }
#pragma unroll
            for (int m = 1; m < 64; m <<= 1) {
                s += __shfl_xor(s, m);
                q += __shfl_xor(q, m);
            }
            if (lane == 0) { lnSs[j * 4 + w] = s; lnQq[j * 4 + w] = q; }
        }
    }
    __syncthreads();
#pragma unroll
    for (int r = 0; r < 4; ++r) {
        const int row = rt * 16 + kg * 4 + r;
        const float mu   = lnSs[row] * (1.f / 512.f);
        const float var  = lnQq[row] * (1.f / 512.f) - mu * mu;
        const float rstd = rsqrtf(var + 1e-5f);
        const float o = (hreg[r] - mu) * rstd * grg + brb;
        __builtin_nontemporal_store(o, out + ((size_t)127 * 512 + n0 + row) * 512 + cg);
        hT[(size_t)(n0 + row) * 512 + cg] = hreg[r];
    }
}

// ---------------- launch ----------------
extern "C" void kernel_launch(void* const* d_in, const int* in_sizes, int n_in,
                              void* d_out, int out_size, void* d_ws, size_t ws_size,
                              hipStream_t stream) {
    const float* obs      = (const float*)d_in[0];
    const float* hx       = (const float*)d_in[1];
    const float* on_reset = (const float*)d_in[2];
    const float* W1  = (const float*)d_in[3];
    const float* b1  = (const float*)d_in[4];
    const float* g1  = (const float*)d_in[5];
    const float* be1 = (const float*)d_in[6];
    const float* W2  = (const float*)d_in[7];
    const float* b2  = (const float*)d_in[8];
    const float* g2  = (const float*)d_in[9];
    const float* be2 = (const float*)d_in[10];
    const float* Wih = (const float*)d_in[11];
    const float* Whh = (const float*)d_in[12];
    const float* bih = (const float*)d_in[13];
    const float* bhh = (const float*)d_in[14];
    const float* gr  = (const float*)d_in[15];
    const float* br  = (const float*)d_in[16];

    // workspace layout (bytes) — proven 272,236,544 footprint
    char* ws = (char*)d_ws;
    bf16* W1b  = (bf16*)(ws + 0);                    //   131072 (dead after GEMM1)
    bf16* W2b  = (bf16*)(ws + 131072);               //   524288 (dead after GEMM2)
    bf16* Wihb = (bf16*)(ws + 655360);               //  1572864 (dead after GI GEMM)
    bf16* Whhb = (bf16*)(ws + 2228224);              //  1572864 (LIVE through scan)
    bf16* Y2   = (bf16*)(ws + 3801088);              // 67108864 (GEMM2f out)
    bf16* GI   = (bf16*)(ws + 3801088 + 67108864);   // 201326592 (gi)
    bf16* Y1   = GI;                                 // alias: GI head (dead before GI write)
    bf16* hAb  = (bf16*)(ws + 0);                    //   524288 over dead W1b+W2b
    bf16* hBb  = (bf16*)(ws + 655360);               //   524288 over dead Wihb head
    unsigned* bar = (unsigned*)(ws + 1179648);       //    32768 (16 groups x 16 flags x 128B)

    // weight conversions (tiny)
    f32_to_bf16_vec<<<(8192 + 255) / 256,  256, 0, stream>>>(W1,  W1b,  8192);
    f32_to_bf16_vec<<<(32768 + 255) / 256, 256, 0, stream>>>(W2,  W2b,  32768);
    f32_to_bf16_vec<<<(98304 + 255) / 256, 256, 0, stream>>>(Wih, Wihb, 98304);
    f32_to_bf16_vec<<<(98304 + 255) / 256, 256, 0, stream>>>(Whh, Whhb, 98304);

    // MLP: fused GEMM+bias+relu+LN; first layer converts obs f32 inline
    gemm_ln_fused<128, true ><<<512, 512, 0, stream>>>(obs, W1b, b1, g1, be1, Y1);
    gemm_ln_fused<512, false><<<512, 512, 0, stream>>>(Y1,  W2b, b2, g2, be2, Y2);
    // gi = f2 @ Wih^T + bih
    gemm_xwt<512, false><<<dim3(12, 512), 256, 0, stream>>>(Y2, Wihb, bih, GI, 1536);

    // scan (column-split, LDS-resident Whh, fused output LN, in-register sums)
    hipMemsetAsync(bar, 0, 32768, stream);
    float* out_p = (float*)d_out;
    float* hT_p  = out_p + (size_t)65536 * 512;
    gru_scan17<<<256, 256, 0, stream>>>(GI, on_reset, hx, Whhb, bhh, gr, br,
                                        hAb, hBb, out_p, hT_p, bar);
}

// Round 19
// 743.939 us; speedup vs baseline: 1.4790x; 1.4790x over previous
//
#include <hip/hip_runtime.h>
#include <hip/hip_bf16.h>

using bf16 = __hip_bfloat16;
typedef __attribute__((ext_vector_type(8))) short short8;
typedef __attribute__((ext_vector_type(4))) float f32x4;
typedef __attribute__((ext_vector_type(4))) unsigned int u32x4;

static __device__ __forceinline__ float b2f(unsigned short s) {
    unsigned u = ((unsigned)s) << 16;
    return __builtin_bit_cast(float, u);
}
static __device__ __forceinline__ short f2b(float f) {
    __hip_bfloat16 h = __float2bfloat16(f);
    return __builtin_bit_cast(short, h);
}
static __device__ __forceinline__ void load_lds16(const void* g, void* l) {
    __builtin_amdgcn_global_load_lds(
        (const __attribute__((address_space(1))) void*)g,
        (__attribute__((address_space(3))) void*)l, 16, 0, 0);
}

// ---------------- f32 -> bf16 conversion (8 elems/thread) ----------------
__global__ void f32_to_bf16_vec(const float* __restrict__ in, bf16* __restrict__ out, int n8) {
    int i = blockIdx.x * blockDim.x + threadIdx.x;
    if (i >= n8) return;
    const f32x4* p = (const f32x4*)(in + (size_t)i * 8);
    f32x4 a = p[0], b = p[1];
    short8 o;
    o[0] = f2b(a[0]); o[1] = f2b(a[1]); o[2] = f2b(a[2]); o[3] = f2b(a[3]);
    o[4] = f2b(b[0]); o[5] = f2b(b[1]); o[6] = f2b(b[2]); o[7] = f2b(b[3]);
    *(short8*)(out + (size_t)i * 8) = o;
}

// ---------------- fused GEMM + bias + relu + LayerNorm (Nout = 512) ----------------
template<int K, bool CONV>
__global__ __launch_bounds__(512, 2) void gemm_ln_fused(
    const void* __restrict__ Xv, const bf16* __restrict__ W,
    const float* __restrict__ bias, const float* __restrict__ g,
    const float* __restrict__ be, bf16* __restrict__ Y)
{
    __shared__ char As[8192];     // 128 rows x 64B (swizzled)
    __shared__ char Bs[32768];    // 512 rows x 64B (swizzled)
    __shared__ float lnS[128][4];
    __shared__ float lnQ[128][4];

    const int tid = threadIdx.x;
    const int wv = tid >> 6, lane = tid & 63;
    const int wr = wv >> 2, wc = wv & 3;
    const long Mbase = (long)blockIdx.x * 128;
    const int lc = lane & 15, kgq = lane >> 4;

    f32x4 acc[4][8];
#pragma unroll
    for (int mt = 0; mt < 4; ++mt)
#pragma unroll
        for (int nt = 0; nt < 8; ++nt) acc[mt][nt] = (f32x4){0.f, 0.f, 0.f, 0.f};

    const int rowA_ = tid >> 2, granA_ = tid & 3;

    for (int kb = 0; kb < K / 32; ++kb) {
        __syncthreads();
        {   // stage A: 128 x 64B
            const int sb = (granA_ * 16) ^ (((rowA_ >> 1) & 3) << 4);
            if (CONV) {
                const float* Xf = (const float*)Xv;
                const float* src = Xf + (Mbase + rowA_) * K + kb * 32 + sb / 2;
                f32x4 a0 = *(const f32x4*)src;
                f32x4 a1 = *(const f32x4*)(src + 4);
                short8 o;
                o[0] = f2b(a0[0]); o[1] = f2b(a0[1]); o[2] = f2b(a0[2]); o[3] = f2b(a0[3]);
                o[4] = f2b(a1[0]); o[5] = f2b(a1[1]); o[6] = f2b(a1[2]); o[7] = f2b(a1[3]);
                *(short8*)(As + rowA_ * 64 + granA_ * 16) = o;
            } else {
                const bf16* X = (const bf16*)Xv;
                load_lds16((const char*)X + ((Mbase + rowA_) * K + kb * 32) * 2 + sb,
                           As + tid * 16);
            }
        }
#pragma unroll
        for (int j = 0; j < 4; ++j) {   // stage B: 512 x 64B
            const int idx = j * 512 + tid;
            const int row = idx >> 2, gran = idx & 3;
            const int sb = (gran * 16) ^ (((row >> 1) & 3) << 4);
            load_lds16((const char*)W + ((long)row * K + kb * 32) * 2 + sb,
                       Bs + idx * 16);
        }
        __syncthreads();

        short8 a[4], b[8];
#pragma unroll
        for (int mt = 0; mt < 4; ++mt) {
            const int ar = wr * 64 + mt * 16 + lc;
            a[mt] = *(const short8*)(As + ar * 64 + ((kgq * 16) ^ (((ar >> 1) & 3) << 4)));
        }
#pragma unroll
        for (int nt = 0; nt < 8; ++nt) {
            const int br = wc * 128 + nt * 16 + lc;
            b[nt] = *(const short8*)(Bs + br * 64 + ((kgq * 16) ^ (((br >> 1) & 3) << 4)));
        }
#pragma unroll
        for (int mt = 0; mt < 4; ++mt)
#pragma unroll
            for (int nt = 0; nt < 8; ++nt)
                acc[mt][nt] = __builtin_amdgcn_mfma_f32_16x16x32_bf16(a[mt], b[nt], acc[mt][nt], 0, 0, 0);
    }

    float bcol[8];
#pragma unroll
    for (int nt = 0; nt < 8; ++nt) bcol[nt] = bias[wc * 128 + nt * 16 + lc];

    float sp[4][4], qp[4][4];
#pragma unroll
    for (int mt = 0; mt < 4; ++mt)
#pragma unroll
        for (int r = 0; r < 4; ++r) { sp[mt][r] = 0.f; qp[mt][r] = 0.f; }
#pragma unroll
    for (int mt = 0; mt < 4; ++mt)
#pragma unroll
        for (int nt = 0; nt < 8; ++nt)
#pragma unroll
            for (int r = 0; r < 4; ++r) {
                float v = fmaxf(acc[mt][nt][r] + bcol[nt], 0.f);
                acc[mt][nt][r] = v;
                sp[mt][r] += v; qp[mt][r] += v * v;
            }
#pragma unroll
    for (int m = 1; m < 16; m <<= 1)
#pragma unroll
        for (int mt = 0; mt < 4; ++mt)
#pragma unroll
            for (int r = 0; r < 4; ++r) {
                sp[mt][r] += __shfl_xor(sp[mt][r], m);
                qp[mt][r] += __shfl_xor(qp[mt][r], m);
            }
    if (lc == 0) {
#pragma unroll
        for (int mt = 0; mt < 4; ++mt)
#pragma unroll
            for (int r = 0; r < 4; ++r) {
                const int grow = wr * 64 + mt * 16 + kgq * 4 + r;
                lnS[grow][wc] = sp[mt][r];
                lnQ[grow][wc] = qp[mt][r];
            }
    }
    __syncthreads();

    float gcol[8], becol[8];
#pragma unroll
    for (int nt = 0; nt < 8; ++nt) {
        const int col = wc * 128 + nt * 16 + lc;
        gcol[nt] = g[col]; becol[nt] = be[col];
    }
#pragma unroll
    for (int mt = 0; mt < 4; ++mt)
#pragma unroll
        for (int r = 0; r < 4; ++r) {
            const int grow = wr * 64 + mt * 16 + kgq * 4 + r;
            f32x4 vs = *(const f32x4*)&lnS[grow][0];
            f32x4 vq = *(const f32x4*)&lnQ[grow][0];
            const float s = vs[0] + vs[1] + vs[2] + vs[3];
            const float q = vq[0] + vq[1] + vq[2] + vq[3];
            const float mu   = s * (1.f / 512.f);
            const float var  = q * (1.f / 512.f) - mu * mu;
            const float rstd = rsqrtf(var + 1e-5f);
            bf16* yrow = Y + (Mbase + grow) * 512;
#pragma unroll
            for (int nt = 0; nt < 8; ++nt) {
                const int col = wc * 128 + nt * 16 + lc;
                yrow[col] = __float2bfloat16((acc[mt][nt][r] - mu) * rstd * gcol[nt] + becol[nt]);
            }
        }
}

// ---------------- GEMM: C = X @ W^T + bias (M from blockIdx.y, N from blockIdx.x) ----
template<int K, bool RELU>
__global__ __launch_bounds__(256) void gemm_xwt(
    const bf16* __restrict__ X, const bf16* __restrict__ W,
    const float* __restrict__ bias, bf16* __restrict__ C, int Nout)
{
    __shared__ char As[8192];
    __shared__ char Bs[8192];
    const int tid  = threadIdx.x;
    const int wave = tid >> 6, lane = tid & 63;
    const int wr = wave >> 1, wc = wave & 1;
    const long Mbase = (long)blockIdx.y * 128;
    const int  Nbase = blockIdx.x * 128;
    const int lc = lane & 15, kgq = lane >> 4;

    f32x4 acc[4][4];
#pragma unroll
    for (int i = 0; i < 4; ++i)
#pragma unroll
        for (int j = 0; j < 4; ++j) acc[i][j] = (f32x4){0.f, 0.f, 0.f, 0.f};

    const int row0_ = tid >> 2, gran_ = tid & 3;

    for (int kb = 0; kb < K / 32; ++kb) {
        __syncthreads();
#pragma unroll
        for (int q = 0; q < 2; ++q) {
            const int idx = q * 256 + tid;
            const int row = q * 64 + row0_;
            const int sb = (gran_ * 16) ^ (((row >> 1) & 3) << 4);
            load_lds16((const char*)X + ((Mbase + row) * K + kb * 32) * 2 + sb,
                       As + idx * 16);
            load_lds16((const char*)W + ((long)(Nbase + row) * K + kb * 32) * 2 + sb,
                       Bs + idx * 16);
        }
        __syncthreads();

        short8 a[4], b[4];
#pragma unroll
        for (int mt = 0; mt < 4; ++mt) {
            const int ar = wr * 64 + mt * 16 + lc;
            a[mt] = *(const short8*)(As + ar * 64 + ((kgq * 16) ^ (((ar >> 1) & 3) << 4)));
        }
#pragma unroll
        for (int nt = 0; nt < 4; ++nt) {
            const int br = wc * 64 + nt * 16 + lc;
            b[nt] = *(const short8*)(Bs + br * 64 + ((kgq * 16) ^ (((br >> 1) & 3) << 4)));
        }
#pragma unroll
        for (int mt = 0; mt < 4; ++mt)
#pragma unroll
            for (int nt = 0; nt < 4; ++nt)
                acc[mt][nt] = __builtin_amdgcn_mfma_f32_16x16x32_bf16(a[mt], b[nt], acc[mt][nt], 0, 0, 0);
    }

#pragma unroll
    for (int mt = 0; mt < 4; ++mt) {
        int row0 = wr * 64 + mt * 16 + (lane >> 4) * 4;
#pragma unroll
        for (int nt = 0; nt < 4; ++nt) {
            int col = Nbase + wc * 64 + nt * 16 + (lane & 15);
            float bv = bias[col];
#pragma unroll
            for (int r = 0; r < 4; ++r) {
                float v = acc[mt][nt][r] + bv;
                if (RELU) v = fmaxf(v, 0.f);
                C[(Mbase + row0 + r) * (long)Nout + col] = __float2bfloat16(v);
            }
        }
    }
}

// ---------------- final LayerNorm rows of 512, bf16 -> f32 ----------------
__global__ __launch_bounds__(256) void ln_rows512_f32out(
    const bf16* __restrict__ in, float* __restrict__ out,
    const float* __restrict__ g, const float* __restrict__ be)
{
    const int lane = threadIdx.x & 63;
    const long row = (long)blockIdx.x * 4 + (threadIdx.x >> 6);
    const bf16* rp = in + row * 512;
    short8 v = *(const short8*)&rp[lane * 8];
    float x[8]; float s = 0.f, sq = 0.f;
#pragma unroll
    for (int j = 0; j < 8; ++j) { x[j] = b2f((unsigned short)v[j]); s += x[j]; sq += x[j] * x[j]; }
#pragma unroll
    for (int m = 1; m < 64; m <<= 1) { s += __shfl_xor(s, m); sq += __shfl_xor(sq, m); }
    float mu   = s * (1.f / 512.f);
    float var  = sq * (1.f / 512.f) - mu * mu;
    float rstd = rsqrtf(var + 1e-5f);
    float* op = out + row * 512 + lane * 8;
#pragma unroll
    for (int c4 = 0; c4 < 2; ++c4) {
        f32x4 o;
#pragma unroll
        for (int j = 0; j < 4; ++j) {
            int c = lane * 8 + c4 * 4 + j;
            o[j] = (x[c4 * 4 + j] - mu) * rstd * g[c] + be[c];
        }
        *(f32x4*)(op + c4 * 4) = o;
    }
}

// ---------------- GRU scan v14 (PROVEN): no-inv scan, sc1 read-through h staging ----
__global__ __launch_bounds__(256, 1) void gru_scan14(
    const bf16* __restrict__ gi, const float* __restrict__ on_reset,
    const float* __restrict__ hx, const bf16* __restrict__ Whh,
    const float* __restrict__ bhh,
    bf16* __restrict__ hA, bf16* __restrict__ hB,
    bf16* __restrict__ h_all, float* __restrict__ hT,
    unsigned* __restrict__ bar)
{
    __shared__ bf16 Wl[96 * 512];   // 98304 B, XOR-swizzled storage
    __shared__ bf16 hS[32 * 512];   // 32768 B, XOR-swizzled storage

    const int tid = threadIdx.x;
    const int bid = blockIdx.x;
    const int xcd = bid & 7, sub = bid >> 3;
    const int g   = xcd * 2 + (sub & 1);          // batch-chunk 0..15
    const int cc  = sub >> 1;                     // col-chunk 0..15
    const int n0 = g * 32, c0 = cc * 32;
    unsigned* gflags = bar + g * 512;             // 16 flags x 128B stride
    unsigned* myflag = gflags + cc * 32;

    const int w = tid >> 6, lane = tid & 63;
    const int lc = lane & 15, kg = lane >> 4;
    const int rt = w >> 1, hh = w & 1;
    const int cg = c0 + hh * 16 + lc;

    char* Wlb = (char*)Wl;
    char* hSb = (char*)hS;

    // ---- Wl: DMA the 96-row Whh slice once ----
    {
        const char* Wb = (const char*)Whh;
#pragma unroll
        for (int i2 = 0; i2 < 24; ++i2) {
            const int i = i2 * 256 + tid;
            const int row = i >> 6, l16 = i & 63;
            const int gRow = (row >> 5) * 512 + c0 + (row & 31);
            load_lds16(Wb + (size_t)gRow * 1024 + ((l16 * 16) ^ ((row & 7) << 4)),
                       Wlb + i * 16);
        }
    }

    const float bhr = bhh[cg], bhz = bhh[512 + cg], bhn = bhh[1024 + cg];

    // ---- h0 init ----
    float hreg[4];
#pragma unroll
    for (int r = 0; r < 4; ++r) {
        const int row = rt * 16 + kg * 4 + r;
        const float m0 = on_reset[n0 + row];
        float v = hx[(size_t)(n0 + row) * 512 + cg];
        hreg[r] = v;
        hA[(size_t)(n0 + row) * 512 + cg] = __float2bfloat16(v * m0);
    }
    __syncthreads();
    asm volatile("s_waitcnt vmcnt(0)" ::: "memory");
    if (tid == 0)   // prologue publish: RELEASE (one wbl2 flushes plain hA stores)
        __hip_atomic_store(myflag, 1u, __ATOMIC_RELEASE, __HIP_MEMORY_SCOPE_AGENT);

#pragma unroll 1
    for (int t = 0; t < 128; ++t) {
        const bf16* hcur = (t & 1) ? hB : hA;
        bf16*       hnxt = (t & 1) ? hA : hB;

        // ---- gi + masks issued early (overlap the poll) ----
        float irv[4], izv[4], inv_[4], mcur[4], mnx[4];
#pragma unroll
        for (int r = 0; r < 4; ++r) {
            const int row = rt * 16 + kg * 4 + r;
            const unsigned short* gp =
                (const unsigned short*)gi + ((size_t)t * 512 + n0 + row) * 1536;
            irv[r]  = b2f(__builtin_nontemporal_load(gp + cg));
            izv[r]  = b2f(__builtin_nontemporal_load(gp + 512 + cg));
            inv_[r] = b2f(__builtin_nontemporal_load(gp + 1024 + cg));
            mcur[r] = on_reset[(size_t)t * 512 + n0 + row];
            mnx[r]  = (t < 127) ? on_reset[(size_t)(t + 1) * 512 + n0 + row] : 1.f;
        }

        // ---- distributed-flag barrier: sc0/sc1 read-through poll, NO inv ----
        if (w == 0) {
            const unsigned tgt = (unsigned)(t + 1);
            const unsigned* fp = gflags + (lane & 15) * 32;
            for (;;) {
                unsigned v = tgt;
                if (lane < 16) {
                    asm volatile("global_load_dword %0, %1, off sc0 sc1\n\t"
                                 "s_waitcnt vmcnt(0)"
                                 : "=v"(v) : "v"(fp) : "memory");
                }
                if (__all(v >= tgt)) break;
                __builtin_amdgcn_s_sleep(2);
            }
        }
        __syncthreads();   // all waves held until h_t published by all 16 blocks

        // ---- stage h_t: sc0/sc1 read-through loads -> regs -> swizzled ds_write ----
        {
            const char* hbp = (const char*)hcur + (size_t)n0 * 1024;
            u32x4 hv[8];
#pragma unroll
            for (int j = 0; j < 8; ++j) {
                const int i = j * 256 + tid;
                const int row = i >> 6, l16 = i & 63;
                const char* src = hbp + row * 1024 + l16 * 16;
                asm volatile("global_load_dwordx4 %0, %1, off sc0 sc1"
                             : "=v"(hv[j]) : "v"(src));
            }
            asm volatile("s_waitcnt vmcnt(0)" ::: "memory");
            __builtin_amdgcn_sched_barrier(0);
#pragma unroll
            for (int j = 0; j < 8; ++j) {
                const int i = j * 256 + tid;
                const int row = i >> 6, l16 = i & 63;
                *(u32x4*)(hSb + row * 1024 + ((l16 * 16) ^ ((row & 7) << 4))) = hv[j];
            }
        }
        __syncthreads();   // hS ready for all waves

        // ---- A-frags from hS ----
        short8 aF[16];
        const int arow = rt * 16 + lc;
        const int asw = (arow & 7) << 4;
#pragma unroll
        for (int kc = 0; kc < 16; ++kc)
            aF[kc] = *(const short8*)(hSb + arow * 1024 + ((kc * 64 + kg * 16) ^ asw));

        // ---- MFMA: 3 gates x 16 k-slices (B from LDS-resident Wl) ----
        f32x4 acc[3];
#pragma unroll
        for (int gt = 0; gt < 3; ++gt) acc[gt] = (f32x4){0.f, 0.f, 0.f, 0.f};
#pragma unroll
        for (int gt = 0; gt < 3; ++gt) {
            const int wrow = gt * 32 + hh * 16 + lc;
            const int wsw = (wrow & 7) << 4;
#pragma unroll
            for (int kc = 0; kc < 16; ++kc) {
                short8 bq = *(const short8*)(Wlb + wrow * 1024 + ((kc * 64 + kg * 16) ^ wsw));
                acc[gt] = __builtin_amdgcn_mfma_f32_16x16x32_bf16(aF[kc], bq, acc[gt], 0, 0, 0);
            }
        }

        // ---- gates + h update + stores (write-through exchange) ----
#pragma unroll
        for (int r = 0; r < 4; ++r) {
            const int row = rt * 16 + kg * 4 + r;
            const float hr = acc[0][r] + bhr;
            const float hz = acc[1][r] + bhz;
            const float hn = acc[2][r] + bhn;
            const float rg = 1.f / (1.f + __expf(-(irv[r] + hr)));
            const float zg = 1.f / (1.f + __expf(-(izv[r] + hz)));
            const float e2 = __expf(2.f * (inv_[r] + rg * hn));
            const float ng = 1.f - 2.f / (e2 + 1.f);   // tanh
            const float hv = (1.f - zg) * ng + zg * (hreg[r] * mcur[r]);
            hreg[r] = hv;
            __builtin_nontemporal_store(
                f2b(hv), (short*)&h_all[((size_t)t * 512 + n0 + row) * 512 + cg]);
            if (t < 127) {
                const unsigned short hb16 = (unsigned short)f2b(hv * mnx[r]);
                const unsigned partner = (unsigned)(unsigned short)__shfl_xor((int)hb16, 1);
                if ((lc & 1) == 0) {
                    const unsigned pk = (unsigned)hb16 | (partner << 16);
                    unsigned* dst = (unsigned*)&hnxt[(size_t)(n0 + row) * 512 + cg];
                    asm volatile("global_store_dword %0, %1, off sc0 sc1"
                                 :: "v"(dst), "v"(pk) : "memory");
                }
            }
        }

        if (t < 127) {
            __syncthreads();   // drains vmcnt: all waves' sc1 stores at coherence point
            if (tid == 0) {
                unsigned fv = (unsigned)(t + 2);
                asm volatile("global_store_dword %0, %1, off sc0 sc1"
                             :: "v"(myflag), "v"(fv) : "memory");
            }
        }
    }

    // ---- hT = h_127 (unmasked, f32) ----
#pragma unroll
    for (int r = 0; r < 4; ++r) {
        const int row = rt * 16 + kg * 4 + r;
        hT[(size_t)(n0 + row) * 512 + cg] = hreg[r];
    }
}

// ---------------- launch ----------------
extern "C" void kernel_launch(void* const* d_in, const int* in_sizes, int n_in,
                              void* d_out, int out_size, void* d_ws, size_t ws_size,
                              hipStream_t stream) {
    const float* obs      = (const float*)d_in[0];
    const float* hx       = (const float*)d_in[1];
    const float* on_reset = (const float*)d_in[2];
    const float* W1  = (const float*)d_in[3];
    const float* b1  = (const float*)d_in[4];
    const float* g1  = (const float*)d_in[5];
    const float* be1 = (const float*)d_in[6];
    const float* W2  = (const float*)d_in[7];
    const float* b2  = (const float*)d_in[8];
    const float* g2  = (const float*)d_in[9];
    const float* be2 = (const float*)d_in[10];
    const float* Wih = (const float*)d_in[11];
    const float* Whh = (const float*)d_in[12];
    const float* bih = (const float*)d_in[13];
    const float* bhh = (const float*)d_in[14];
    const float* gr  = (const float*)d_in[15];
    const float* br  = (const float*)d_in[16];

    // workspace layout (bytes) — proven 272,236,544 footprint
    char* ws = (char*)d_ws;
    bf16* W1b  = (bf16*)(ws + 0);                    //   131072 (dead after GEMM1)
    bf16* W2b  = (bf16*)(ws + 131072);               //   524288 (dead after GEMM2)
    bf16* Wihb = (bf16*)(ws + 655360);               //  1572864 (dead after GI GEMM)
    bf16* Whhb = (bf16*)(ws + 2228224);              //  1572864 (LIVE through scan)
    bf16* Y2   = (bf16*)(ws + 3801088);              // 67108864 (GEMM2f out; later h_all)
    bf16* GI   = (bf16*)(ws + 3801088 + 67108864);   // 201326592 (gi)
    bf16* Y1   = GI;                                 // alias: GI head (dead before GI write)
    bf16* hAb  = (bf16*)(ws + 0);                    //   524288 over dead W1b+W2b
    bf16* hBb  = (bf16*)(ws + 655360);               //   524288 over dead Wihb head
    unsigned* bar = (unsigned*)(ws + 1179648);       //    32768 (16 groups x 16 flags x 128B)
    bf16* h_all = Y2;                                // alias: Y2 dead after GI GEMM

    // weight conversions (tiny)
    f32_to_bf16_vec<<<(8192 + 255) / 256,  256, 0, stream>>>(W1,  W1b,  8192);
    f32_to_bf16_vec<<<(32768 + 255) / 256, 256, 0, stream>>>(W2,  W2b,  32768);
    f32_to_bf16_vec<<<(98304 + 255) / 256, 256, 0, stream>>>(Wih, Wihb, 98304);
    f32_to_bf16_vec<<<(98304 + 255) / 256, 256, 0, stream>>>(Whh, Whhb, 98304);

    // MLP: fused GEMM+bias+relu+LN; first layer converts obs f32 inline
    gemm_ln_fused<128, true ><<<512, 512, 0, stream>>>(obs, W1b, b1, g1, be1, Y1);
    gemm_ln_fused<512, false><<<512, 512, 0, stream>>>(Y1,  W2b, b2, g2, be2, Y2);
    // gi = f2 @ Wih^T + bih   (grid: col-tiles fastest -> A-panel L2/L3 locality)
    gemm_xwt<512, false><<<dim3(12, 512), 256, 0, stream>>>(Y2, Wihb, bih, GI, 1536);

    // scan (column-split, LDS-resident Whh, sc1 read-through h staging, no inv)
    hipMemsetAsync(bar, 0, 32768, stream);
    float* out_p = (float*)d_out;
    float* hT_p  = out_p + (size_t)65536 * 512;
    gru_scan14<<<256, 256, 0, stream>>>(GI, on_reset, hx, Whhb, bhh,
                                        hAb, hBb, h_all, hT_p, bar);

    // final LN: bf16 h_all -> f32 out
    ln_rows512_f32out<<<16384, 256, 0, stream>>>(h_all, out_p, gr, br);
}